// Round 10
// baseline (67.827 us; speedup 1.0000x reference)
//
#include <hip/hip_runtime.h>
#include <math.h>

#define KC 3
#define S 12
#define SS 1728
#define AB 32
#define TLEN 64
#define NTHREADS 896
#define NWAVES 14
#define NACT 864            // 432 slices x 2 threads
#define LN2F 0.69314718055994530942f

__global__ __launch_bounds__(NTHREADS, 4)   // 4 waves/SIMD -> 128 VGPR cap
void hmm_fwd_kernel(const int* __restrict__ ys,
                    const float* __restrict__ transition,  // [3][12][12]
                    const float* __restrict__ emission,    // [3][12][32]
                    const float* __restrict__ choice,      // [3]
                    const float* __restrict__ prior,       // [3][12]
                    float* __restrict__ out)
{
    // A planes in natural order n = 144 s0 + 12 s1 + s2
    __shared__ __align__(16) float APL[KC][SS];
    // beta in three chain orderings, rows of 12 words:
    //   B0[q0=12s1+s2][i=s0], B1[q1=12s0+s2][i=s1], B2[q2=12s0+s1][i=s2]
    __shared__ __align__(16) float B0[SS], B1[SS], B2[SS];
    __shared__ __align__(16) float ECt[KC][AB][16];  // slot (j/6)*8 + j%6
    __shared__ __align__(16) float T_s[KC][S][16];   // slot (j/6)*8 + j%6
    __shared__ float p_lin[KC][S];
    __shared__ float c_lin[KC];
    __shared__ int   ys_s[TLEN];
    __shared__ float wsum[NWAVES];

    const int tid = threadIdx.x;

    // ---------------- setup: linear-space tables ----------------
    if (tid < TLEN) ys_s[tid] = ys[tid];

    if (tid == 0) {
        float m = fmaxf(fmaxf(choice[0], choice[1]), choice[2]);
        float e0 = __expf(choice[0]-m), e1 = __expf(choice[1]-m), e2 = __expf(choice[2]-m);
        float inv = 1.f / (e0+e1+e2);
        c_lin[0] = e0*inv; c_lin[1] = e1*inv; c_lin[2] = e2*inv;
    }
    if (tid >= 1 && tid < 1 + KC) {
        int k = tid - 1;
        float m = -INFINITY;
        #pragma unroll
        for (int i = 0; i < S; ++i) m = fmaxf(m, prior[k*S + i]);
        float ev[S]; float s = 0.f;
        #pragma unroll
        for (int i = 0; i < S; ++i) { ev[i] = __expf(prior[k*S + i] - m); s += ev[i]; }
        float inv = 1.f / s;
        #pragma unroll
        for (int i = 0; i < S; ++i) p_lin[k][i] = ev[i] * inv;
    }
    if (tid >= 64 && tid < 64 + KC*S) {
        int r = tid - 64;
        int k = r / S, i = r % S;
        const float* row = transition + (k*S + i)*S;
        float m = -INFINITY;
        #pragma unroll
        for (int j = 0; j < S; ++j) m = fmaxf(m, row[j]);
        float ev[S]; float s = 0.f;
        #pragma unroll
        for (int j = 0; j < S; ++j) { ev[j] = __expf(row[j] - m); s += ev[j]; }
        float inv = 1.f / s;
        #pragma unroll
        for (int j = 0; j < S; ++j) T_s[k][i][(j/6)*8 + (j%6)] = ev[j] * inv;
    }
    if (tid >= 128 && tid < 128 + KC*S) {    // emission -> ECt = C[k]*softmax
        int r = tid - 128;
        int k = r / S, sj = r % S;
        float cm = fmaxf(fmaxf(choice[0], choice[1]), choice[2]);
        float ce = __expf(choice[k]-cm) /
                   (__expf(choice[0]-cm) + __expf(choice[1]-cm) + __expf(choice[2]-cm));
        const float* row = emission + (k*S + sj)*AB;
        float m = -INFINITY;
        #pragma unroll
        for (int a = 0; a < AB; ++a) m = fmaxf(m, row[a]);
        float ev[AB]; float s = 0.f;
        #pragma unroll
        for (int a = 0; a < AB; ++a) { ev[a] = __expf(row[a] - m); s += ev[a]; }
        float inv = ce / s;
        const int slot = (sj / 6) * 8 + (sj % 6);
        #pragma unroll
        for (int a = 0; a < AB; ++a) ECt[k][a][slot] = ev[a] * inv;
    }
    __syncthreads();

    // ---------------- per-thread statics ----------------
    const bool act = tid < NACT;
    const int ct = act ? tid : (NACT - 1);
    const int sl = ct >> 1;            // slice 0..431
    const int h  = ct & 1;             // output half: columns 6h..6h+5
    const int sk = sl / 144;           // chain
    const int q  = sl % 144;
    const int qh = q / 12, ql = q % 12;

    // phase-2 gather base: all chains read their own ordering, contiguous rows
    const float* const rp = ((sk == 0) ? B0 : (sk == 1) ? B1 : B2) + 12*q;
    // A-plane write base/stride (natural order)
    const int wstr = (sk == 0) ? 144 : (sk == 1) ? 12 : 1;
    const int wbas = ((sk == 0) ? q : (sk == 1) ? 144*qh + ql : 12*q) + wstr*6*h;
    float* const wap = &APL[sk][wbas];
    const float* const ecp = &ECt[sk][0][8*h];

    // phase-1 statics (thread owns natural states n, n+1; n = 2*tid)
    const int n  = 2 * ct;
    const int s0 = n / 144, s1 = (n / 12) % 12, s2 = n % 12;   // s2 even
    const int w1b = 144*s0 + 12*s2 + s1;   // B1 position of (n); +12 for n+1
    const int w0b = 144*s1 + 12*s2 + s0;   // B0 position of (n); +12 for n+1

    // T columns 6h..6h+5 in registers. VOLATILE loads: not rematerializable,
    // so the values must stay live in VGPRs (budget ~114 < 128 cap).
    float Trg[S][6];
    {
        #pragma unroll
        for (int i = 0; i < S; ++i) {
            volatile const float* tv = &T_s[sk][i][8*h];
            Trg[i][0] = tv[0]; Trg[i][1] = tv[1]; Trg[i][2] = tv[2];
            Trg[i][3] = tv[3]; Trg[i][4] = tv[4]; Trg[i][5] = tv[5];
        }
    }

    // init A planes: thread owns natural states n, n+1
    if (act) {
        const float pp = p_lin[0][s0] * p_lin[1][s1];
        const float pA = pp * p_lin[2][s2], pB = pp * p_lin[2][s2+1];
        #pragma unroll
        for (int k = 0; k < KC; ++k) {
            float2 v; v.x = pA * c_lin[k]; v.y = pB * c_lin[k];
            *reinterpret_cast<float2*>(&APL[k][n]) = v;
        }
    }
    __syncthreads();

    // ---------------- 64 steps, 2 barriers each ----------------
    float logR = 0.f, invR = 1.f;

    #pragma unroll 1
    for (int t = 0; t < TLEN; ++t) {
        const int y = ys_s[t];

        if (act) {
            // phase 1: beta for states n, n+1 -> three orderings
            float2 a0 = *reinterpret_cast<const float2*>(&APL[0][n]);
            float2 a1 = *reinterpret_cast<const float2*>(&APL[1][n]);
            float2 a2 = *reinterpret_cast<const float2*>(&APL[2][n]);
            float2 b;
            b.x = (a0.x + a1.x + a2.x) * invR;
            b.y = (a0.y + a1.y + a2.y) * invR;
            *reinterpret_cast<float2*>(&B2[n]) = b;
            B1[w1b] = b.x; B1[w1b + 12] = b.y;
            B0[w0b] = b.x; B0[w0b + 12] = b.y;
        }
        __syncthreads();   // barrier A: B0/B1/B2 ready

        float acc0=0.f, acc1=0.f, acc2=0.f, acc3=0.f, acc4=0.f, acc5=0.f;
        if (act) {
            // E half-row (broadcast)
            float4 e03 = *reinterpret_cast<const float4*>(&ecp[y*16]);
            float2 e45 = *reinterpret_cast<const float2*>(&ecp[y*16 + 4]);

            // 12 betas: contiguous b128 in own ordering (uniform for all chains)
            float4 r0 = *reinterpret_cast<const float4*>(&rp[0]);
            float4 r1 = *reinterpret_cast<const float4*>(&rp[4]);
            float4 r2 = *reinterpret_cast<const float4*>(&rp[8]);
            float bv[S];
            bv[0]=r0.x; bv[1]=r0.y; bv[2] =r0.z; bv[3] =r0.w;
            bv[4]=r1.x; bv[5]=r1.y; bv[6] =r1.z; bv[7] =r1.w;
            bv[8]=r2.x; bv[9]=r2.y; bv[10]=r2.z; bv[11]=r2.w;

            #pragma unroll
            for (int i = 0; i < S; ++i) {
                const float bb = bv[i];
                acc0 = __builtin_fmaf(bb, Trg[i][0], acc0);
                acc1 = __builtin_fmaf(bb, Trg[i][1], acc1);
                acc2 = __builtin_fmaf(bb, Trg[i][2], acc2);
                acc3 = __builtin_fmaf(bb, Trg[i][3], acc3);
                acc4 = __builtin_fmaf(bb, Trg[i][4], acc4);
                acc5 = __builtin_fmaf(bb, Trg[i][5], acc5);
            }
            acc0 *= e03.x; acc1 *= e03.y; acc2 *= e03.z;
            acc3 *= e03.w; acc4 *= e45.x; acc5 *= e45.y;

            // write 6 outputs to own plane (natural order)
            if (sk == 2) {
                if (h == 0) {
                    *reinterpret_cast<float4*>(&wap[0]) = make_float4(acc0, acc1, acc2, acc3);
                    *reinterpret_cast<float2*>(&wap[4]) = make_float2(acc4, acc5);
                } else {
                    *reinterpret_cast<float2*>(&wap[0]) = make_float2(acc0, acc1);
                    *reinterpret_cast<float4*>(&wap[2]) = make_float4(acc2, acc3, acc4, acc5);
                }
            } else {
                wap[0*wstr] = acc0; wap[1*wstr] = acc1; wap[2*wstr] = acc2;
                wap[3*wstr] = acc3; wap[4*wstr] = acc4; wap[5*wstr] = acc5;
            }
        }

        if ((t & 7) == 7) {
            float part = acc0 + acc1 + acc2 + acc3 + acc4 + acc5;   // 0 for inactive
            part += __shfl_xor(part, 32); part += __shfl_xor(part, 16);
            part += __shfl_xor(part, 8);  part += __shfl_xor(part, 4);
            part += __shfl_xor(part, 2);  part += __shfl_xor(part, 1);
            if ((tid & 63) == 0) wsum[tid >> 6] = part;
        }
        __syncthreads();   // barrier B: A planes (and wsum) visible

        if ((t & 7) == 7 && t < TLEN-1) {
            float R = 0.f;
            #pragma unroll
            for (int w = 0; w < NWAVES; ++w) R += wsum[w];
            invR = __builtin_amdgcn_rcpf(R);
            logR += __log2f(R);
        } else {
            invR = 1.f;
        }
    }

    // final: total mass at t=63 is in wsum (its normalizer never applied)
    if (tid == 0) {
        float R = 0.f;
        #pragma unroll
        for (int w = 0; w < NWAVES; ++w) R += wsum[w];
        out[0] = LN2F * (__log2f(R) + logR);
    }
}

extern "C" void kernel_launch(void* const* d_in, const int* in_sizes, int n_in,
                              void* d_out, int out_size, void* d_ws, size_t ws_size,
                              hipStream_t stream) {
    const int*   ys         = (const int*)  d_in[0];
    const float* transition = (const float*)d_in[1];
    const float* emission   = (const float*)d_in[2];
    const float* choice     = (const float*)d_in[3];
    const float* prior      = (const float*)d_in[4];
    float* out = (float*)d_out;

    hipLaunchKernelGGL(hmm_fwd_kernel, dim3(1), dim3(NTHREADS), 0, stream,
                       ys, transition, emission, choice, prior, out);
}

// Round 11
// 61.316 us; speedup vs baseline: 1.1062x; 1.1062x over previous
//
#include <hip/hip_runtime.h>
#include <math.h>

#define KC 3
#define S 12
#define SS 1728
#define AB 32
#define TLEN 64
#define NTHREADS 896
#define NWAVES 14
#define NACT 864            // 432 slices x 2 threads
#define LN2F 0.69314718055994530942f

__global__ __launch_bounds__(NTHREADS, 4)   // 4 waves/SIMD -> 128 VGPR cap
void hmm_fwd_kernel(const int* __restrict__ ys,
                    const float* __restrict__ transition,  // [3][12][12]
                    const float* __restrict__ emission,    // [3][12][32]
                    const float* __restrict__ choice,      // [3]
                    const float* __restrict__ prior,       // [3][12]
                    float* __restrict__ out,
                    float* __restrict__ Tw)                // d_ws: T table, [k][i][16] f32
{
    // A planes in natural state order n = s0*144 + s1*12 + s2
    __shared__ __align__(16) float APL[KC][SS];
    __shared__ __align__(16) float BETA[SS];
    __shared__ __align__(16) float ECt[KC][AB][16];  // [k][y][8h+m], padded rows
    __shared__ float p_lin[KC][S];
    __shared__ float c_lin[KC];
    __shared__ int   ys_s[TLEN];
    __shared__ float wsum[NWAVES];

    const int tid = threadIdx.x;

    // ---------------- setup: stage inputs, build linear-space tables ----------------
    if (tid < TLEN) ys_s[tid] = ys[tid];

    if (tid == 0) {
        float m = fmaxf(fmaxf(choice[0], choice[1]), choice[2]);
        float e0 = __expf(choice[0]-m), e1 = __expf(choice[1]-m), e2 = __expf(choice[2]-m);
        float inv = 1.f / (e0+e1+e2);
        c_lin[0] = e0*inv; c_lin[1] = e1*inv; c_lin[2] = e2*inv;
    }
    if (tid >= 1 && tid < 1 + KC) {
        int k = tid - 1;
        float m = -INFINITY;
        #pragma unroll
        for (int i = 0; i < S; ++i) m = fmaxf(m, prior[k*S + i]);
        float ev[S]; float s = 0.f;
        #pragma unroll
        for (int i = 0; i < S; ++i) { ev[i] = __expf(prior[k*S + i] - m); s += ev[i]; }
        float inv = 1.f / s;
        #pragma unroll
        for (int i = 0; i < S; ++i) p_lin[k][i] = ev[i] * inv;
    }
    if (tid >= 64 && tid < 64 + KC*S) {
        // transition rows -> softmax probs, written to GLOBAL d_ws
        // layout: row (k,i) at Tw[(k*12+i)*16], cols j<6 -> slot j, j>=6 -> slot j+2
        int r = tid - 64;
        int k = r / S, i = r % S;
        const float* row = transition + (k*S + i)*S;
        float m = -INFINITY;
        #pragma unroll
        for (int j = 0; j < S; ++j) m = fmaxf(m, row[j]);
        float ev[S]; float s = 0.f;
        #pragma unroll
        for (int j = 0; j < S; ++j) { ev[j] = __expf(row[j] - m); s += ev[j]; }
        float inv = 1.f / s;
        float* tg = Tw + (k*S + i)*16;
        #pragma unroll
        for (int j = 0; j < S; ++j) tg[(j < 6) ? j : j + 2] = ev[j] * inv;
    }
    if (tid >= 128 && tid < 128 + KC*S) {    // emission -> ECt[k][y][8h+m] = C[k]*softmax
        int r = tid - 128;
        int k = r / S, sj = r % S;
        float cm = fmaxf(fmaxf(choice[0], choice[1]), choice[2]);
        float ce = __expf(choice[k]-cm) /
                   (__expf(choice[0]-cm) + __expf(choice[1]-cm) + __expf(choice[2]-cm));
        const float* row = emission + (k*S + sj)*AB;
        float m = -INFINITY;
        #pragma unroll
        for (int a = 0; a < AB; ++a) m = fmaxf(m, row[a]);
        float ev[AB]; float s = 0.f;
        #pragma unroll
        for (int a = 0; a < AB; ++a) { ev[a] = __expf(row[a] - m); s += ev[a]; }
        float inv = ce / s;
        const int slot = (sj / 6) * 8 + (sj % 6);
        #pragma unroll
        for (int a = 0; a < AB; ++a) ECt[k][a][slot] = ev[a] * inv;
    }
    __syncthreads();   // drains vmcnt -> Tw stores visible to all lanes' loads

    // ---------------- per-thread statics ----------------
    const bool act = tid < NACT;
    const int ct = act ? tid : (NACT - 1);
    const int sl = ct >> 1;            // slice 0..431
    const int h  = ct & 1;             // output half: columns 6h..6h+5
    const int sk = sl / 144;           // chain
    const int q  = sl % 144;
    const int qh = q / 12, ql = q % 12;

    // beta gather base (natural order), per chain
    const int rdb = (sk == 0) ? q : (sk == 1) ? 144*qh + ql : 12*q;
    // A write base/stride for own chain
    const int wstr = (sk == 0) ? 144 : (sk == 1) ? 12 : 1;
    const int wbas = rdb + wstr * 6 * h;           // j = 6h + m
    float* const wap = &APL[sk][wbas];
    const float* const ecp = &ECt[sk][0][8*h];

    // T columns 6h..6h+5, loaded from GLOBAL (VMEM pipe; LDS pipe untouched).
    // If the compiler hoists these into registers: even better.
    const float* const tgb = Tw + (sk*S)*16 + 8*h;
    float Trg[S][6];
    #pragma unroll
    for (int i = 0; i < S; ++i) {
        float4 t03 = *reinterpret_cast<const float4*>(&tgb[16*i]);
        float2 t45 = *reinterpret_cast<const float2*>(&tgb[16*i + 4]);
        Trg[i][0] = t03.x; Trg[i][1] = t03.y; Trg[i][2] = t03.z;
        Trg[i][3] = t03.w; Trg[i][4] = t45.x; Trg[i][5] = t45.y;
    }

    // init A planes: thread p owns natural states 2p, 2p+1 (s2 even, no carry)
    if (act) {
        const int sA = 2*tid;
        const int a0 = sA/144, b0 = (sA/12)%12, c0 = sA%12;
        const float pp = p_lin[0][a0]*p_lin[1][b0];
        const float pA = pp*p_lin[2][c0], pB = pp*p_lin[2][c0+1];
        #pragma unroll
        for (int k = 0; k < KC; ++k) {
            float2 v; v.x = pA*c_lin[k]; v.y = pB*c_lin[k];
            *reinterpret_cast<float2*>(&APL[k][sA]) = v;
        }
    }
    __syncthreads();

    // ---------------- 64 steps, 2 barriers each ----------------
    float logR = 0.f, invR = 1.f;
    const int s2p = 2*tid;

    #pragma unroll 1
    for (int t = 0; t < TLEN; ++t) {
        const int y = ys_s[t];

        if (act) {
            // phase 1: beta for 2 states (b64 reads/write, conflict-free)
            float2 a0 = *reinterpret_cast<const float2*>(&APL[0][s2p]);
            float2 a1 = *reinterpret_cast<const float2*>(&APL[1][s2p]);
            float2 a2 = *reinterpret_cast<const float2*>(&APL[2][s2p]);
            float2 b;
            b.x = (a0.x + a1.x + a2.x) * invR;
            b.y = (a0.y + a1.y + a2.y) * invR;
            *reinterpret_cast<float2*>(&BETA[s2p]) = b;
        }
        __syncthreads();   // barrier A: BETA ready

        float acc0=0.f, acc1=0.f, acc2=0.f, acc3=0.f, acc4=0.f, acc5=0.f;
        if (act) {
            // E half-row (broadcast, padded to 8 words, no branch)
            float4 e03 = *reinterpret_cast<const float4*>(&ecp[y*16]);
            float2 e45 = *reinterpret_cast<const float2*>(&ecp[y*16 + 4]);

            // gather 12 betas (pair lanes broadcast the same addresses)
            float bv[S];
            if (sk == 0) {
                #pragma unroll
                for (int i = 0; i < S; ++i) bv[i] = BETA[rdb + 144*i];
            } else if (sk == 1) {
                #pragma unroll
                for (int i = 0; i < S; ++i) bv[i] = BETA[rdb + 12*i];
            } else {
                float4 r0 = *reinterpret_cast<const float4*>(&BETA[rdb + 0]);
                float4 r1 = *reinterpret_cast<const float4*>(&BETA[rdb + 4]);
                float4 r2 = *reinterpret_cast<const float4*>(&BETA[rdb + 8]);
                bv[0]=r0.x; bv[1]=r0.y; bv[2] =r0.z; bv[3] =r0.w;
                bv[4]=r1.x; bv[5]=r1.y; bv[6] =r1.z; bv[7] =r1.w;
                bv[8]=r2.x; bv[9]=r2.y; bv[10]=r2.z; bv[11]=r2.w;
            }

            #pragma unroll
            for (int i = 0; i < S; ++i) {
                const float bb = bv[i];
                acc0 = __builtin_fmaf(bb, Trg[i][0], acc0);
                acc1 = __builtin_fmaf(bb, Trg[i][1], acc1);
                acc2 = __builtin_fmaf(bb, Trg[i][2], acc2);
                acc3 = __builtin_fmaf(bb, Trg[i][3], acc3);
                acc4 = __builtin_fmaf(bb, Trg[i][4], acc4);
                acc5 = __builtin_fmaf(bb, Trg[i][5], acc5);
            }
            acc0 *= e03.x; acc1 *= e03.y; acc2 *= e03.z;
            acc3 *= e03.w; acc4 *= e45.x; acc5 *= e45.y;

            // write 6 outputs to own plane
            if (sk == 2) {
                if (h == 0) {
                    *reinterpret_cast<float4*>(&wap[0]) = make_float4(acc0, acc1, acc2, acc3);
                    *reinterpret_cast<float2*>(&wap[4]) = make_float2(acc4, acc5);
                } else {
                    *reinterpret_cast<float2*>(&wap[0]) = make_float2(acc0, acc1);
                    *reinterpret_cast<float4*>(&wap[2]) = make_float4(acc2, acc3, acc4, acc5);
                }
            } else {
                wap[0*wstr] = acc0; wap[1*wstr] = acc1; wap[2*wstr] = acc2;
                wap[3*wstr] = acc3; wap[4*wstr] = acc4; wap[5*wstr] = acc5;
            }
        }

        if ((t & 7) == 7) {
            float part = acc0 + acc1 + acc2 + acc3 + acc4 + acc5;   // 0 for inactive
            part += __shfl_xor(part, 32); part += __shfl_xor(part, 16);
            part += __shfl_xor(part, 8);  part += __shfl_xor(part, 4);
            part += __shfl_xor(part, 2);  part += __shfl_xor(part, 1);
            if ((tid & 63) == 0) wsum[tid >> 6] = part;
        }
        __syncthreads();   // barrier B: A planes (and wsum) visible

        if ((t & 7) == 7 && t < TLEN-1) {
            float R = 0.f;
            #pragma unroll
            for (int w = 0; w < NWAVES; ++w) R += wsum[w];
            invR = __builtin_amdgcn_rcpf(R);
            logR += __log2f(R);
        } else {
            invR = 1.f;
        }
    }

    // final: total mass at t=63 is in wsum (its normalizer never applied)
    if (tid == 0) {
        float R = 0.f;
        #pragma unroll
        for (int w = 0; w < NWAVES; ++w) R += wsum[w];
        out[0] = LN2F * (__log2f(R) + logR);
    }
}

extern "C" void kernel_launch(void* const* d_in, const int* in_sizes, int n_in,
                              void* d_out, int out_size, void* d_ws, size_t ws_size,
                              hipStream_t stream) {
    const int*   ys         = (const int*)  d_in[0];
    const float* transition = (const float*)d_in[1];
    const float* emission   = (const float*)d_in[2];
    const float* choice     = (const float*)d_in[3];
    const float* prior      = (const float*)d_in[4];
    float* out = (float*)d_out;
    float* Tw  = (float*)d_ws;   // 3*12*16 floats = 2304 B

    hipLaunchKernelGGL(hmm_fwd_kernel, dim3(1), dim3(NTHREADS), 0, stream,
                       ys, transition, emission, choice, prior, out, Tw);
}